// Round 2
// baseline (3478.420 us; speedup 1.0000x reference)
//
#include <hip/hip_runtime.h>
#include <hip/hip_fp16.h>
#include <hip/hip_cooperative_groups.h>
#include <math.h>

namespace cg = cooperative_groups;

#define HW_ (512 * 512)

__device__ inline float2 cadd(float2 a, float2 b){ return make_float2(a.x+b.x, a.y+b.y); }
__device__ inline float2 csub(float2 a, float2 b){ return make_float2(a.x-b.x, a.y-b.y); }
__device__ inline float2 cmulf(float2 a, float2 b){ return make_float2(a.x*b.x-a.y*b.y, a.x*b.y+a.y*b.x); }
__device__ inline float bf2f(unsigned short u){ return __uint_as_float(((unsigned int)u) << 16); }
__device__ inline unsigned short f2bf(float f){
    unsigned int x = __float_as_uint(f);
    x += 0x7fffu + ((x >> 16) & 1u);
    return (unsigned short)(x >> 16);
}

// ---------- 8-point DFT in registers, natural-order output ----------
template<bool INV>
__device__ inline void dft8(const float2 a[8], float2 X[8]) {
    const float C = 0.70710678118654752440f;
    float2 t0 = cadd(a[0], a[4]), t4 = csub(a[0], a[4]);
    float2 t1 = cadd(a[1], a[5]), d1 = csub(a[1], a[5]);
    float2 t2 = cadd(a[2], a[6]), d2 = csub(a[2], a[6]);
    float2 t3 = cadd(a[3], a[7]), d3 = csub(a[3], a[7]);
    float2 t5, t6, t7;
    if (!INV) {
        t5 = make_float2(C*(d1.x + d1.y), C*(d1.y - d1.x));   // * (C,-C)
        t6 = make_float2(d2.y, -d2.x);                        // * -i
        t7 = make_float2(C*(d3.y - d3.x), -C*(d3.x + d3.y));  // * (-C,-C)
    } else {
        t5 = make_float2(C*(d1.x - d1.y), C*(d1.y + d1.x));   // * (C,C)
        t6 = make_float2(-d2.y, d2.x);                        // * +i
        t7 = make_float2(-C*(d3.x + d3.y), C*(d3.x - d3.y));  // * (-C,C)
    }
    float2 u0 = cadd(t0, t2), u2 = csub(t0, t2);
    float2 u1 = cadd(t1, t3), e3 = csub(t1, t3);
    float2 u3 = INV ? make_float2(-e3.y, e3.x) : make_float2(e3.y, -e3.x);
    float2 u4 = cadd(t4, t6), u6 = csub(t4, t6);
    float2 u5 = cadd(t5, t7), e7 = csub(t5, t7);
    float2 u7 = INV ? make_float2(-e7.y, e7.x) : make_float2(e7.y, -e7.x);
    X[0] = cadd(u0, u1); X[4] = csub(u0, u1);
    X[2] = cadd(u2, u3); X[6] = csub(u2, u3);
    X[1] = cadd(u4, u5); X[5] = csub(u4, u5);
    X[3] = cadd(u6, u7); X[7] = csub(u6, u7);
}

// ---------- 512-pt FFT: radix-8^3 Stockham, registers + 2 LDS exchanges ----------
// Entry: a[j] = x[lane + 64*j].  Exit: a[k] = X[lane + 64*k] (natural order).
// xch: 576-float2 wave-private LDS region. T1/T2 are FORWARD twiddle bases
// exp(-2pi i lane/512), exp(-2pi i (lane>>3)/64); conjugated internally if INV.
template<bool INV>
__device__ inline void fft512_reg(float2 a[8], float2* __restrict__ xch,
                                  int lane, float2 T1, float2 T2)
{
    float2 tw1 = INV ? make_float2(T1.x, -T1.y) : T1;
    float2 tw2 = INV ? make_float2(T2.x, -T2.y) : T2;
    const int rdo = lane + (lane >> 3);        // read offset base (skewed)
    float2 b[8];

    // stage 1: n=512, s=1, p=lane
    dft8<INV>(a, b);
    { float2 w = tw1;
      #pragma unroll
      for (int k = 1; k < 8; ++k) { b[k] = cmulf(b[k], w); w = cmulf(w, tw1); } }
    #pragma unroll
    for (int k = 0; k < 8; ++k) xch[9*lane + k] = b[k];   // e=8t+k -> e+(e>>3)
    __asm__ volatile("s_waitcnt lgkmcnt(0)" ::: "memory");
    #pragma unroll
    for (int j = 0; j < 8; ++j) a[j] = xch[rdo + 72*j];   // e=t+64j

    // stage 2: n=64, s=8, p=lane>>3, q=lane&7
    dft8<INV>(a, b);
    { float2 w = tw2;
      #pragma unroll
      for (int k = 1; k < 8; ++k) { b[k] = cmulf(b[k], w); w = cmulf(w, tw2); } }
    { const int wbase = (lane & 7) + 72 * (lane >> 3);    // e=q+64p+8k -> q+72p+9k
      #pragma unroll
      for (int k = 0; k < 8; ++k) xch[wbase + 9*k] = b[k]; }
    __asm__ volatile("s_waitcnt lgkmcnt(0)" ::: "memory");
    #pragma unroll
    for (int j = 0; j < 8; ++j) b[j] = xch[rdo + 72*j];

    // stage 3: n=8, s=64, p=0 (no twiddle), output natural order
    dft8<INV>(b, a);
}

// ---------- constants: propT/greenT/MT in TRANSPOSED [w][h] layout ----------
__global__ __launch_bounds__(256)
void k_pre(const float* __restrict__ kz, const float* __restrict__ otfa,
           const float* __restrict__ gmask, const float* __restrict__ otfp,
           float2* __restrict__ propT, float2* __restrict__ greenT,
           float2* __restrict__ MT)
{
    __shared__ float2 tp[32*33], tg[32*33], tm[32*33];
    const int tid = threadIdx.x;
    const int w0 = (blockIdx.x & 15) << 5;
    const int h0 = (blockIdx.x >> 4) << 5;
    const int ww = tid & 31, hh = tid >> 5;   // hh 0..7
    #pragma unroll
    for (int p = 0; p < 4; ++p) {
        int h = hh + p*8;
        int idx = (h0 + h)*512 + w0 + ww;
        float k = kz[idx];
        float sn, cs; __sincosf(k * 0.1f, &sn, &cs);
        float inv2 = 0.5f / k * gmask[idx];
        float phase = otfp[idx] - k * 0.5f;     // otfp + kz*DZ*(20-25)
        float s2, c2; __sincosf(phase, &s2, &c2);
        float oa = otfa[idx];
        tp[h*33 + ww] = make_float2(cs, sn);
        tg[h*33 + ww] = make_float2(-sn*inv2, cs*inv2);
        tm[h*33 + ww] = make_float2(oa*c2, oa*s2);
    }
    __syncthreads();
    #pragma unroll
    for (int p = 0; p < 4; ++p) {
        int wrow = hh + p*8;
        size_t o = (size_t)(w0 + wrow)*512 + h0 + ww;
        propT[o]  = tp[ww*33 + wrow];
        greenT[o] = tg[ww*33 + wrow];
        MT[o]     = tm[ww*33 + wrow];
    }
}

// ---------- sample [B,H,W,S] f32 -> sampT [S,B,H,W] bf16 complex ----------
__global__ __launch_bounds__(256)
void k_transpose(const float* __restrict__ sre, const float* __restrict__ sim,
                 ushort2* __restrict__ sampT)
{
    __shared__ __align__(16) ushort2 tile[40 * 128];
    const int bh = blockIdx.x >> 2;          // b*512 + h
    const int chunk = blockIdx.x & 3;
    const int b = bh >> 9, h = bh & 511;
    const int w0 = chunk << 7;
    const float4* sre4 = (const float4*)(sre + (size_t)bh * 20480) + chunk * 1280;
    const float4* sim4 = (const float4*)(sim + (size_t)bh * 20480) + chunk * 1280;
    #pragma unroll
    for (int i = 0; i < 5; ++i) {
        int j = threadIdx.x + (i << 8);      // 0..1279
        float4 re = sre4[j];
        float4 im = sim4[j];
        int w = j / 10;                      // w within chunk (0..127)
        int m = j - w * 10;                  // s-quad index (0..9), s = 4m+t
        ushort2* row = &tile[(m << 2) * 128 + (w ^ ((m & 7) << 2))];
        row[0]   = make_ushort2(f2bf(re.x), f2bf(im.x));
        row[128] = make_ushort2(f2bf(re.y), f2bf(im.y));
        row[256] = make_ushort2(f2bf(re.z), f2bf(im.z));
        row[384] = make_ushort2(f2bf(re.w), f2bf(im.w));
    }
    __syncthreads();
    #pragma unroll
    for (int i = 0; i < 5; ++i) {
        int j = threadIdx.x + (i << 8);      // 0..1279
        int s = j >> 5, q = j & 31;          // s-row, w-quad
        int qp = q ^ ((s >> 2) & 7);         // undo swizzle
        uint4 v = *(const uint4*)&tile[(s << 7) + (qp << 2)];
        *(uint4*)&sampT[(((size_t)s * 4 + b) * 512 + h) * 512 + w0 + (q << 2)] = v;
    }
}

// ---------- persistent cooperative kernel: whole slice loop ----------
// Grid 256 blocks x 512 threads (1 block/CU, co-resident via cooperative launch).
// Row role:   wave = row rrow = bk*8+wv (2048 rows).
// Col role:   block owns 8 columns (b = bk>>6, w = (bk&63)*8 + wv), FIXED across
//             slices -> inc, prop, green columns live in REGISTERS all 40 slices.
// Per slice: R(s): fld2 = fp16(Fr(Br(fldA)*slab*DZ/512));  gsync;
//            C(s): s5 = Fc(fld2); inc = prop*inc + green*s5 (last: *=M);
//                  fldA = Bc(inc)/512;  gsync.
// 4 FFT passes/slice (was 5), no incT memory, no per-slice prop/green reloads.
__global__ __launch_bounds__(512, 2)
void k_loop(float2* __restrict__ fldA, ushort2* __restrict__ fld2,
            const float* __restrict__ pwre, const float* __restrict__ pwim,
            const ushort2* __restrict__ sampT,
            const float2* __restrict__ propT, const float2* __restrict__ greenT,
            const float2* __restrict__ MT, float* __restrict__ out)
{
    cg::grid_group grid = cg::this_grid();
    __shared__ float2  bufA[512 * 9];   // xch regions (8 x 576) / fldA staging
    __shared__ ushort2 buf2[512 * 9];   // fld2 staging (col phase)

    const int tid = threadIdx.x, lane = tid & 63, wv = tid >> 6;
    const int bk = blockIdx.x;
    float2* xch = &bufA[wv * 576];

    float s1, c1, s2, c2;
    __sincosf(-6.2831853071795864769f * (float)lane / 512.0f, &s1, &c1);
    __sincosf(-6.2831853071795864769f * (float)(lane >> 3) / 64.0f, &s2, &c2);
    const float2 T1 = make_float2(c1, s1), T2 = make_float2(c2, s2);

    // row role ids
    const int rrow = bk * 8 + wv;              // 0..2047
    const int rb = rrow >> 9, rh = rrow & 511;
    const size_t rbase = ((size_t)rb * 512 + rh) * 512;
    // col role ids
    const int cb = bk >> 6, w0 = (bk & 63) << 3;
    const int w = w0 + wv;
    const size_t cgbase = (size_t)cb * HW_ + w0;
    const int cc = tid & 7, chb = tid >> 3;
    const size_t pbase = (size_t)w * 512;

    // persistent col-role state
    float2 inc[8], pr[8], gr[8];
    #pragma unroll
    for (int k = 0; k < 8; ++k) {
        pr[k] = propT[pbase + lane + (k << 6)];
        gr[k] = greenT[pbase + lane + (k << 6)];
    }

    float2 a[8];

    // ---- R0: fldA = Fr(planewave)
    #pragma unroll
    for (int j = 0; j < 8; ++j) {
        int ww = lane + (j << 6);
        a[j] = make_float2(pwre[rbase + ww], pwim[rbase + ww]);
    }
    fft512_reg<false>(a, xch, lane, T1, T2);
    #pragma unroll
    for (int j = 0; j < 8; ++j) fldA[rbase + lane + (j << 6)] = a[j];
    grid.sync();

    // ---- Cinit: inc = Fc(fldA)  (fldA == Bc(inc)/512 already holds)
    #pragma unroll
    for (int j = 0; j < 8; ++j) {
        int h = chb + (j << 6);
        bufA[h*9 + cc] = fldA[cgbase + (size_t)h * 512 + cc];
    }
    __syncthreads();
    #pragma unroll
    for (int j = 0; j < 8; ++j) inc[j] = bufA[(lane + (j << 6)) * 9 + wv];
    __syncthreads();
    fft512_reg<false>(inc, xch, lane, T1, T2);
    __syncthreads();                    // xch free before row phase reuses bufA

    // prefetch sample slice 0 for row role
    ushort2 smp[8];
    {
        const size_t sb0 = (((size_t)0 * 4 + rb) * 512 + rh) * 512;
        #pragma unroll
        for (int j = 0; j < 8; ++j) smp[j] = sampT[sb0 + lane + (j << 6)];
    }

    const float scale = 0.1f / 512.0f;  // DZ * (1/512 column-inverse norm)
    const float inv = 1.0f / 512.0f;

    for (int s = 0; s < 40; ++s) {
        // ---- R(s): fld2 = fp16( Fr( Br(fldA) * slab ) )
        #pragma unroll
        for (int j = 0; j < 8; ++j) a[j] = fldA[rbase + lane + (j << 6)];
        fft512_reg<true>(a, xch, lane, T1, T2);       // Br (unnormalized)
        #pragma unroll
        for (int j = 0; j < 8; ++j) {
            float sr = bf2f(smp[j].x), si = bf2f(smp[j].y);
            float2 v = a[j];
            a[j] = make_float2((v.x*sr - v.y*si) * scale, (v.x*si + v.y*sr) * scale);
        }
        if (s < 39) {                                  // prefetch next slice
            const size_t sbn = (((size_t)(s+1) * 4 + rb) * 512 + rh) * 512;
            #pragma unroll
            for (int j = 0; j < 8; ++j) smp[j] = sampT[sbn + lane + (j << 6)];
        }
        fft512_reg<false>(a, xch, lane, T1, T2);      // Fr
        #pragma unroll
        for (int j = 0; j < 8; ++j) {
            float2 v = a[j];
            fld2[rbase + lane + (j << 6)] =
                make_ushort2(__half_as_ushort(__float2half(v.x)),
                             __half_as_ushort(__float2half(v.y)));
        }
        grid.sync();

        // ---- C(s): s5 = Fc(fld2); inc = prop*inc + green*s5; fldA = Bc(inc)/512
        #pragma unroll
        for (int j = 0; j < 8; ++j) {
            int h = chb + (j << 6);
            buf2[h*9 + cc] = fld2[cgbase + (size_t)h * 512 + cc];
        }
        __syncthreads();
        #pragma unroll
        for (int j = 0; j < 8; ++j) {
            ushort2 u = buf2[(lane + (j << 6)) * 9 + wv];
            a[j] = make_float2(__half2float(__ushort_as_half(u.x)),
                               __half2float(__ushort_as_half(u.y)));
        }
        fft512_reg<false>(a, xch, lane, T1, T2);      // s5 (xch wave-private; ok)
        #pragma unroll
        for (int k = 0; k < 8; ++k) {
            float2 nw = make_float2(
                pr[k].x*inc[k].x - pr[k].y*inc[k].y + gr[k].x*a[k].x - gr[k].y*a[k].y,
                pr[k].x*inc[k].y + pr[k].y*inc[k].x + gr[k].x*a[k].y + gr[k].y*a[k].x);
            inc[k] = nw;
        }
        if (s == 39) {
            #pragma unroll
            for (int k = 0; k < 8; ++k) inc[k] = cmulf(inc[k], MT[pbase + lane + (k << 6)]);
        }
        #pragma unroll
        for (int k = 0; k < 8; ++k) a[k] = inc[k];
        fft512_reg<true>(a, xch, lane, T1, T2);       // Bc (unnormalized)
        __syncthreads();                               // all waves done with xch
        #pragma unroll
        for (int k = 0; k < 8; ++k)
            bufA[(lane + (k << 6)) * 9 + wv] = make_float2(a[k].x * inv, a[k].y * inv);
        __syncthreads();
        #pragma unroll
        for (int j = 0; j < 8; ++j) {
            int h = chb + (j << 6);
            fldA[cgbase + (size_t)h * 512 + cc] = bufA[h*9 + cc];
        }
        grid.sync();
    }

    // ---- Final: out = |Br(fldA)|/512, rows 32..479, cols 32..479
    if (wv < 7) {
        const int r = bk * 7 + wv;                    // 0..1791
        const int ob = r / 448, oh = r - ob * 448;    // h = oh + 32
        const size_t fbase = ((size_t)ob * 512 + oh + 32) * 512;
        #pragma unroll
        for (int j = 0; j < 8; ++j) a[j] = fldA[fbase + lane + (j << 6)];
        fft512_reg<true>(a, xch, lane, T1, T2);
        float* orow = out + ((size_t)ob * 448 + oh) * 448;
        #pragma unroll
        for (int j = 0; j < 8; ++j) {
            int ww = lane + (j << 6);
            if (ww >= 32 && ww < 480) {
                float2 v = a[j];
                orow[ww - 32] = sqrtf(v.x*v.x + v.y*v.y) * (1.0f / 512.0f);
            }
        }
    }
}

extern "C" void kernel_launch(void* const* d_in, const int* in_sizes, int n_in,
                              void* d_out, int out_size, void* d_ws, size_t ws_size,
                              hipStream_t stream)
{
    (void)in_sizes; (void)n_in; (void)out_size; (void)ws_size;
    const float* sre   = (const float*)d_in[0];
    const float* simg  = (const float*)d_in[1];
    const float* pwre  = (const float*)d_in[2];
    const float* pwim  = (const float*)d_in[3];
    const float* kz    = (const float*)d_in[4];
    const float* otfa  = (const float*)d_in[5];
    const float* gmask = (const float*)d_in[6];
    const float* otfp  = (const float*)d_in[7];

    char* ws = (char*)d_ws;
    size_t off = 0;
    float2* propT  = (float2*)(ws + off); off += (size_t)HW_ * 8;
    float2* greenT = (float2*)(ws + off); off += (size_t)HW_ * 8;
    float2* MT     = (float2*)(ws + off); off += (size_t)HW_ * 8;
    float2* fldA   = (float2*)(ws + off); off += (size_t)4 * HW_ * 8;
    ushort2* fld2  = (ushort2*)(ws + off); off += (size_t)4 * HW_ * 4;
    ushort2* sampT = (ushort2*)(ws + off);
    float* outp    = (float*)d_out;

    k_pre<<<256, 256, 0, stream>>>(kz, otfa, gmask, otfp, propT, greenT, MT);
    k_transpose<<<8192, 256, 0, stream>>>(sre, simg, sampT);

    void* kargs[] = { (void*)&fldA, (void*)&fld2, (void*)&pwre, (void*)&pwim,
                      (void*)&sampT, (void*)&propT, (void*)&greenT, (void*)&MT,
                      (void*)&outp };
    hipLaunchCooperativeKernel((const void*)k_loop, dim3(256), dim3(512),
                               kargs, 0, stream);
}